// Round 4
// baseline (906.241 us; speedup 1.0000x reference)
//
#include <hip/hip_runtime.h>

#define B_ 16
#define C_ 64
#define H_ 192
#define W_ 192
#define TR 4
#define TC 48

typedef short bf16x8 __attribute__((ext_vector_type(8)));
typedef float f32x4  __attribute__((ext_vector_type(4)));

static __device__ __forceinline__ unsigned short f2bf(float f) {
    union { float f; unsigned u; } v; v.f = f;
    unsigned r = v.u + 0x7fff + ((v.u >> 16) & 1);   // RNE
    return (unsigned short)(r >> 16);
}
static __device__ __forceinline__ float bf2f(unsigned short u) {
    union { unsigned u; float f; } v; v.u = ((unsigned)u) << 16; return v.f;
}
// swizzled xs index (shorts): pixel p (0..299), channel ch (0..63)
// 300 rows x 128B; 16B granule column rotated by p&7 -> conflict-free b128
static __device__ __forceinline__ int xsw(int p, int ch) {
    return p * 64 + (((ch >> 3) ^ (p & 7)) << 3) + (ch & 7);
}

// ---- prep: kernel-MLP (blocks 0..15) + conv_w transpose->bf16 (blocks 16..159) ----
__global__ void prep(const float* __restrict__ k_v, const float* __restrict__ W1,
                     const float* __restrict__ W2, const float* __restrict__ conv_w,
                     float* __restrict__ kern, unsigned short* __restrict__ wT) {
    const int blk = blockIdx.x, tid = threadIdx.x;
    if (blk < 16) {
        __shared__ float kv[64], hid[64];
        const int b = blk;
        if (tid < 64) kv[tid] = k_v[b * 64 + tid];
        __syncthreads();
        if (tid < 64) {
            const float4* w4 = (const float4*)(W1 + tid * 64);
            float s = 0.f;
#pragma unroll
            for (int k4 = 0; k4 < 16; ++k4) {
                float4 f = w4[k4];
                s += kv[k4 * 4 + 0] * f.x + kv[k4 * 4 + 1] * f.y
                   + kv[k4 * 4 + 2] * f.z + kv[k4 * 4 + 3] * f.w;
            }
            hid[tid] = s > 0.f ? s : 0.1f * s;
        }
        __syncthreads();
        for (int o = tid; o < 576; o += 256) {
            const float4* w4 = (const float4*)(W2 + o * 64);
            float t = 0.f;
#pragma unroll
            for (int k4 = 0; k4 < 16; ++k4) {
                float4 f = w4[k4];
                t += hid[k4 * 4 + 0] * f.x + hid[k4 * 4 + 1] * f.y
                   + hid[k4 * 4 + 2] * f.z + hid[k4 * 4 + 3] * f.w;
            }
            kern[b * 576 + o] = t;
        }
    } else {
        int idx = (blk - 16) * 256 + tid;     // 144*256 = 36864 exact
        int tap = idx >> 12;
        int rem = idx & 4095;
        int n = rem >> 6, k = rem & 63;
        wT[idx] = f2bf(conv_w[(n * 64 + k) * 9 + tap]);
    }
}

// ---- fused: MFMA static conv + depthwise + epilogue; bx SERIAL per block ----
// Round-0 per-tile code, unchanged. One block now owns a FULL output row strip
// (loops bx=0..3): both halves of every 256B write granule are produced by the
// same CU ~3us apart -> dirty line still L2-resident -> writes merge -> one
// writeback (round 0 measured WRITE = 2.06x output = zero cross-block merge).
__global__ __launch_bounds__(256, 3)
void fused_conv(const float* __restrict__ x, const unsigned short* __restrict__ wT,
                const float* __restrict__ kern, const float* __restrict__ conv_b,
                float* __restrict__ out) {
    // XCD-locality remap: xcd = linear_id % 8 (round-robin dispatch).
    // 768 blocks = 96/XCD; XCD g owns batches {2g,2g+1}; by-neighbors (row-halo
    // sharers) are dispatch-distance 1 on the same XCD.
    const int L = blockIdx.x + 48 * blockIdx.y;
    const int g = L & 7;
    const int s = L >> 3;                 // 0..95
    const int by = s % 48;
    const int b  = (g << 1) + (s / 48);   // 0..15

    const int tid  = threadIdx.x;
    const int lane = tid & 63;
    const int wv   = tid >> 6;
    const int n0   = lane & 15;
    const int q    = lane >> 4;
    const int r0 = by * TR;

    __shared__ __align__(16) unsigned short xs[6 * 50 * 64];   // 38400 B

    const unsigned short* wbase = wT + n0 * 64 + q * 8;
    bf16x8 bcur[4][2], bnxt[4][2];

#pragma unroll 1
    for (int bx = 0; bx < 4; ++bx) {
        const int c0 = bx * TC;

        // B fragments for tap 0: load before the barrier (overlap with staging)
#pragma unroll
        for (int nt = 0; nt < 4; ++nt)
#pragma unroll
            for (int ks = 0; ks < 2; ++ks)
                bcur[nt][ks] = *(const bf16x8*)(wbase + nt * 1024 + ks * 32);

        // ---- stage interior cols (sc 1..48) ----
        for (int u = tid; u < 576; u += 256) {
            int chg  = u / 72;
            int rest = u - chg * 72;
            int row  = rest / 12;
            int cg   = rest - row * 12;
            int gr   = r0 + row - 1;
            bool in  = (gr >= 0 && gr < H_);
            int grc  = in ? gr : 0;
            const float* xp = x + ((size_t)(b * 64 + chg * 8) * H_ + grc) * W_ + c0 + cg * 4;
            float4 f[8];
#pragma unroll
            for (int j = 0; j < 8; ++j)
                f[j] = in ? *(const float4*)(xp + j * H_ * W_) : make_float4(0.f, 0.f, 0.f, 0.f);
#pragma unroll
            for (int e = 0; e < 4; ++e) {
                int p = row * 50 + 1 + cg * 4 + e;
                union { bf16x8 v; unsigned short s8[8]; } pk;
#pragma unroll
                for (int j = 0; j < 8; ++j) pk.s8[j] = f2bf(((const float*)&f[j])[e]);
                *(bf16x8*)(xs + xsw(p, chg * 8)) = pk.v;
            }
        }
        // ---- stage edge cols sc=0 / sc=49 ----
        if (tid < 96) {
            int chg  = tid / 12;
            int rest = tid - chg * 12;
            int row  = rest >> 1;
            int sc   = (rest & 1) ? 49 : 0;
            int gr = r0 + row - 1, gc = c0 + sc - 1;
            bool in = (gr >= 0 && gr < H_ && gc >= 0 && gc < W_);
            union { bf16x8 v; unsigned short s8[8]; } pk;
#pragma unroll
            for (int j = 0; j < 8; ++j) {
                float vv = 0.f;
                if (in) vv = x[((size_t)(b * 64 + chg * 8 + j) * H_ + gr) * W_ + gc];
                pk.s8[j] = f2bf(vv);
            }
            *(bf16x8*)(xs + xsw(row * 50 + sc, chg * 8)) = pk.v;
        }

        f32x4 acc[3][4];
#pragma unroll
        for (int i = 0; i < 3; ++i)
#pragma unroll
            for (int j = 0; j < 4; ++j) acc[i][j] = (f32x4){0.f, 0.f, 0.f, 0.f};

        __syncthreads();   // staging complete

        // ---- K loop: 9 taps; B ping-pong register prefetch (tap+1 in flight) ----
#pragma unroll
        for (int tap = 0; tap < 9; ++tap) {
            if (tap < 8) {
#pragma unroll
                for (int nt = 0; nt < 4; ++nt)
#pragma unroll
                    for (int ks = 0; ks < 2; ++ks)
                        bnxt[nt][ks] = *(const bf16x8*)(wbase + (tap + 1) * 4096 + nt * 1024 + ks * 32);
            }
            const int dr = tap / 3, dc = tap % 3;
#pragma unroll
            for (int cb = 0; cb < 3; ++cb) {
                const int p = (wv + dr) * 50 + cb * 16 + n0 + dc;
                bf16x8 a0 = *(const bf16x8*)(xs + p * 64 + ((q ^ (p & 7)) << 3));
                bf16x8 a1 = *(const bf16x8*)(xs + p * 64 + (((q + 4) ^ (p & 7)) << 3));
#pragma unroll
                for (int nt = 0; nt < 4; ++nt) {
                    acc[cb][nt] = __builtin_amdgcn_mfma_f32_16x16x32_bf16(a0, bcur[nt][0], acc[cb][nt], 0, 0, 0);
                    acc[cb][nt] = __builtin_amdgcn_mfma_f32_16x16x32_bf16(a1, bcur[nt][1], acc[cb][nt], 0, 0, 0);
                }
            }
            if (tap < 8) {
#pragma unroll
                for (int nt = 0; nt < 4; ++nt)
#pragma unroll
                    for (int ks = 0; ks < 2; ++ks)
                        bcur[nt][ks] = bnxt[nt][ks];
            }
        }

        // ---- epilogue: depthwise from xs + kern/bias (L2-hot); plain stores ----
        const float* kp = kern + b * 576;
#pragma unroll
        for (int nt = 0; nt < 4; ++nt) {
            const int n = nt * 16 + n0;
            float kw[9];
#pragma unroll
            for (int j = 0; j < 9; ++j) kw[j] = kp[n * 9 + j];
            const float bias = conv_b[n];
            const int gn = n >> 3, n7 = n & 7;
#pragma unroll
            for (int cb = 0; cb < 3; ++cb) {
                const int colb = cb * 16 + q * 4;
                float xw[3][6];
#pragma unroll
                for (int d = 0; d < 3; ++d)
#pragma unroll
                    for (int cc = 0; cc < 6; ++cc) {
                        int p = (wv + d) * 50 + colb + cc;
                        xw[d][cc] = bf2f(xs[p * 64 + ((gn ^ (p & 7)) << 3) + n7]);
                    }
                float4 st;
#pragma unroll
                for (int r = 0; r < 4; ++r) {
                    float dw = 0.f;
#pragma unroll
                    for (int d = 0; d < 3; ++d)
#pragma unroll
                        for (int e = 0; e < 3; ++e)
                            dw += kw[d * 3 + e] * xw[d][r + e];
                    float v = (dw > 0.f ? dw : 0.1f * dw) + acc[cb][nt][r] + bias;
                    ((float*)&st)[r] = v;
                }
                *(float4*)(out + ((size_t)(b * 64 + n) * H_ + (r0 + wv)) * W_ + c0 + colb) = st;
            }
        }

        if (bx < 3) __syncthreads();   // xs reused by next tile's staging
    }
}

extern "C" void kernel_launch(void* const* d_in, const int* in_sizes, int n_in,
                              void* d_out, int out_size, void* d_ws, size_t ws_size,
                              hipStream_t stream) {
    const float* x      = (const float*)d_in[0];
    const float* k_v    = (const float*)d_in[1];
    const float* W1     = (const float*)d_in[2];
    const float* W2     = (const float*)d_in[3];
    const float* conv_w = (const float*)d_in[4];
    const float* conv_b = (const float*)d_in[5];
    float* outp = (float*)d_out;

    float* kern        = (float*)d_ws;                               // 36864 B
    unsigned short* wT = (unsigned short*)((char*)d_ws + 40960);     // 73728 B

    prep<<<160, 256, 0, stream>>>(k_v, W1, W2, conv_w, kern, wT);
    dim3 grid(48, 16);
    fused_conv<<<grid, 256, 0, stream>>>(x, wT, kern, conv_b, outp);
}

// Round 5
// 393.092 us; speedup vs baseline: 2.3054x; 2.3054x over previous
//
#include <hip/hip_runtime.h>

#define B_ 16
#define C_ 64
#define H_ 192
#define W_ 192
#define TR 4
#define TC 64

typedef short bf16x8 __attribute__((ext_vector_type(8)));
typedef float f32x4  __attribute__((ext_vector_type(4)));

static __device__ __forceinline__ unsigned short f2bf(float f) {
    union { float f; unsigned u; } v; v.f = f;
    unsigned r = v.u + 0x7fff + ((v.u >> 16) & 1);   // RNE
    return (unsigned short)(r >> 16);
}
static __device__ __forceinline__ float bf2f(unsigned short u) {
    union { unsigned u; float f; } v; v.u = ((unsigned)u) << 16; return v.f;
}
// swizzled xs index (shorts): pixel p (0..395), channel ch (0..63)
// rows of 128B; 16B granule column rotated by p&7 -> conflict-free b128
static __device__ __forceinline__ int xsw(int p, int ch) {
    return p * 64 + (((ch >> 3) ^ (p & 7)) << 3) + (ch & 7);
}

// ---- prep: kernel-MLP (blocks 0..15) + conv_w transpose->bf16 (blocks 16..159) ----
__global__ void prep(const float* __restrict__ k_v, const float* __restrict__ W1,
                     const float* __restrict__ W2, const float* __restrict__ conv_w,
                     float* __restrict__ kern, unsigned short* __restrict__ wT) {
    const int blk = blockIdx.x, tid = threadIdx.x;
    if (blk < 16) {
        __shared__ float kv[64], hid[64];
        const int b = blk;
        if (tid < 64) kv[tid] = k_v[b * 64 + tid];
        __syncthreads();
        if (tid < 64) {
            const float4* w4 = (const float4*)(W1 + tid * 64);
            float s = 0.f;
#pragma unroll
            for (int k4 = 0; k4 < 16; ++k4) {
                float4 f = w4[k4];
                s += kv[k4 * 4 + 0] * f.x + kv[k4 * 4 + 1] * f.y
                   + kv[k4 * 4 + 2] * f.z + kv[k4 * 4 + 3] * f.w;
            }
            hid[tid] = s > 0.f ? s : 0.1f * s;
        }
        __syncthreads();
        for (int o = tid; o < 576; o += 256) {
            const float4* w4 = (const float4*)(W2 + o * 64);
            float t = 0.f;
#pragma unroll
            for (int k4 = 0; k4 < 16; ++k4) {
                float4 f = w4[k4];
                t += hid[k4 * 4 + 0] * f.x + hid[k4 * 4 + 1] * f.y
                   + hid[k4 * 4 + 2] * f.z + hid[k4 * 4 + 3] * f.w;
            }
            kern[b * 576 + o] = t;
        }
    } else {
        int idx = (blk - 16) * 256 + tid;     // 144*256 = 36864 exact
        int tap = idx >> 12;
        int rem = idx & 4095;
        int n = rem >> 6, k = rem & 63;
        wT[idx] = f2bf(conv_w[(n * 64 + k) * 9 + tap]);
    }
}

// ---- fused: MFMA static conv + depthwise + epilogue; one barrier; XCD swizzle ----
// TC=64 rerun WITHOUT register squeeze: round-2's identical geometry was
// spill-contaminated (FETCH/WRITE signature matches round-3's forced-spill run;
// live set acc[4][4]+bcur+bnxt ~= 115 regs vs 84 allocated). launch_bounds(256)
// with NO min-wave clause frees the allocator (cap 256); occupancy stays
// LDS-limited at 3 blocks/CU (3x50688 = 152KB), same as round 0.
// Geometry goal: each 256B output granule written whole by ONE block in 4
// back-to-back stores -> L2 merge -> WRITE amp 2.06x -> ~1.0x.
__global__ __launch_bounds__(256)
void fused_conv(const float* __restrict__ x, const unsigned short* __restrict__ wT,
                const float* __restrict__ kern, const float* __restrict__ conv_b,
                float* __restrict__ out) {
    // XCD-locality remap: xcd = linear_id % 8 (round-robin dispatch).
    // 2304 blocks = 288 per XCD; XCD g owns batches {2g, 2g+1}.
    const int L = blockIdx.x + 3 * (blockIdx.y + 48 * blockIdx.z);
    const int g = L & 7;
    const int s = L >> 3;                 // 0..287
    const int bx = s % 3;
    const int sl = s / 3;                 // 0..95
    const int by = sl % 48;
    const int b  = (g << 1) + (sl / 48);  // 0..15

    const int tid  = threadIdx.x;
    const int lane = tid & 63;
    const int wv   = tid >> 6;
    const int n0   = lane & 15;
    const int q    = lane >> 4;
    const int r0 = by * TR;
    const int c0 = bx * TC;

    __shared__ __align__(16) unsigned short xs[6 * 66 * 64];   // 50688 B

    // B fragments for tap 0 load before the barrier (overlap with staging)
    const unsigned short* wbase = wT + n0 * 64 + q * 8;
    bf16x8 bcur[4][2], bnxt[4][2];
#pragma unroll
    for (int nt = 0; nt < 4; ++nt)
#pragma unroll
        for (int ks = 0; ks < 2; ++ks)
            bcur[nt][ks] = *(const bf16x8*)(wbase + nt * 1024 + ks * 32);

    // ---- stage interior cols (sc 1..64): 6 rows x 16 colgroups x 8 chgroups ----
    for (int u = tid; u < 768; u += 256) {
        int chg  = u / 96;
        int rest = u - chg * 96;
        int row  = rest >> 4;
        int cg   = rest & 15;
        int gr   = r0 + row - 1;
        bool in  = (gr >= 0 && gr < H_);
        int grc  = in ? gr : 0;
        const float* xp = x + ((size_t)(b * 64 + chg * 8) * H_ + grc) * W_ + c0 + cg * 4;
        float4 f[8];
#pragma unroll
        for (int j = 0; j < 8; ++j)
            f[j] = in ? *(const float4*)(xp + j * H_ * W_) : make_float4(0.f, 0.f, 0.f, 0.f);
#pragma unroll
        for (int e = 0; e < 4; ++e) {
            int p = row * 66 + 1 + cg * 4 + e;
            union { bf16x8 v; unsigned short s8[8]; } pk;
#pragma unroll
            for (int j = 0; j < 8; ++j) pk.s8[j] = f2bf(((const float*)&f[j])[e]);
            *(bf16x8*)(xs + xsw(p, chg * 8)) = pk.v;
        }
    }
    // ---- stage edge cols sc=0 / sc=65 ----
    if (tid < 96) {
        int chg  = tid / 12;
        int rest = tid - chg * 12;
        int row  = rest >> 1;
        int sc   = (rest & 1) ? 65 : 0;
        int gr = r0 + row - 1, gc = c0 + sc - 1;
        bool in = (gr >= 0 && gr < H_ && gc >= 0 && gc < W_);
        union { bf16x8 v; unsigned short s8[8]; } pk;
#pragma unroll
        for (int j = 0; j < 8; ++j) {
            float vv = 0.f;
            if (in) vv = x[((size_t)(b * 64 + chg * 8 + j) * H_ + gr) * W_ + gc];
            pk.s8[j] = f2bf(vv);
        }
        *(bf16x8*)(xs + xsw(row * 66 + sc, chg * 8)) = pk.v;
    }

    f32x4 acc[4][4];
#pragma unroll
    for (int i = 0; i < 4; ++i)
#pragma unroll
        for (int j = 0; j < 4; ++j) acc[i][j] = (f32x4){0.f, 0.f, 0.f, 0.f};

    __syncthreads();   // the ONE barrier

    // ---- K loop: 9 taps; B ping-pong register prefetch (tap+1 in flight) ----
#pragma unroll
    for (int tap = 0; tap < 9; ++tap) {
        if (tap < 8) {
#pragma unroll
            for (int nt = 0; nt < 4; ++nt)
#pragma unroll
                for (int ks = 0; ks < 2; ++ks)
                    bnxt[nt][ks] = *(const bf16x8*)(wbase + (tap + 1) * 4096 + nt * 1024 + ks * 32);
        }
        const int dr = tap / 3, dc = tap % 3;
#pragma unroll
        for (int cb = 0; cb < 4; ++cb) {
            const int p = (wv + dr) * 66 + cb * 16 + n0 + dc;
            bf16x8 a0 = *(const bf16x8*)(xs + p * 64 + ((q ^ (p & 7)) << 3));
            bf16x8 a1 = *(const bf16x8*)(xs + p * 64 + (((q + 4) ^ (p & 7)) << 3));
#pragma unroll
            for (int nt = 0; nt < 4; ++nt) {
                acc[cb][nt] = __builtin_amdgcn_mfma_f32_16x16x32_bf16(a0, bcur[nt][0], acc[cb][nt], 0, 0, 0);
                acc[cb][nt] = __builtin_amdgcn_mfma_f32_16x16x32_bf16(a1, bcur[nt][1], acc[cb][nt], 0, 0, 0);
            }
        }
        if (tap < 8) {
#pragma unroll
            for (int nt = 0; nt < 4; ++nt)
#pragma unroll
                for (int ks = 0; ks < 2; ++ks)
                    bcur[nt][ks] = bnxt[nt][ks];
        }
    }

    // ---- epilogue: depthwise from xs + kern/bias (L2-hot); plain stores ----
    const float* kp = kern + b * 576;
#pragma unroll
    for (int nt = 0; nt < 4; ++nt) {
        const int n = nt * 16 + n0;
        float kw[9];
#pragma unroll
        for (int j = 0; j < 9; ++j) kw[j] = kp[n * 9 + j];
        const float bias = conv_b[n];
        const int gn = n >> 3, n7 = n & 7;
#pragma unroll
        for (int cb = 0; cb < 4; ++cb) {
            const int colb = cb * 16 + q * 4;
            float xw[3][6];
#pragma unroll
            for (int d = 0; d < 3; ++d)
#pragma unroll
                for (int cc = 0; cc < 6; ++cc) {
                    int p = (wv + d) * 66 + colb + cc;
                    xw[d][cc] = bf2f(xs[p * 64 + ((gn ^ (p & 7)) << 3) + n7]);
                }
            float4 st;
#pragma unroll
            for (int r = 0; r < 4; ++r) {
                float dw = 0.f;
#pragma unroll
                for (int d = 0; d < 3; ++d)
#pragma unroll
                    for (int e = 0; e < 3; ++e)
                        dw += kw[d * 3 + e] * xw[d][r + e];
                float v = (dw > 0.f ? dw : 0.1f * dw) + acc[cb][nt][r] + bias;
                ((float*)&st)[r] = v;
            }
            *(float4*)(out + ((size_t)(b * 64 + n) * H_ + (r0 + wv)) * W_ + c0 + colb) = st;
        }
    }
}

extern "C" void kernel_launch(void* const* d_in, const int* in_sizes, int n_in,
                              void* d_out, int out_size, void* d_ws, size_t ws_size,
                              hipStream_t stream) {
    const float* x      = (const float*)d_in[0];
    const float* k_v    = (const float*)d_in[1];
    const float* W1     = (const float*)d_in[2];
    const float* W2     = (const float*)d_in[3];
    const float* conv_w = (const float*)d_in[4];
    const float* conv_b = (const float*)d_in[5];
    float* outp = (float*)d_out;

    float* kern        = (float*)d_ws;                               // 36864 B
    unsigned short* wT = (unsigned short*)((char*)d_ws + 40960);     // 73728 B

    prep<<<160, 256, 0, stream>>>(k_v, W1, W2, conv_w, kern, wT);
    dim3 grid(3, 48, 16);
    fused_conv<<<grid, 256, 0, stream>>>(x, wT, kern, conv_b, outp);
}